// Round 4
// baseline (2626.180 us; speedup 1.0000x reference)
//
#include <hip/hip_runtime.h>

#define M_NODES 100000
#define N_EDGES 3200000
#define D 128
#define NBUCK 1563            // ceil(100000 / 64) buckets of 64 rows
#define FILL_CHUNK 12288      // edges per block in hist/fill (256 thr * 12 * 4)
#define FILL_BLOCKS 261       // ceil(3.2M / 12288)

// ---------------- workspace layout (bytes) ----------------
#define OFF_SUP16  0ull            // 100000*64 u32 (paired bf16) = 25,600,000
#define OFF_BCNT   25600000ull     // 1563 int (+pad)
#define OFF_BSTART 25606400ull     // 1564 int (+pad)
#define OFF_BPOS   25612800ull     // 1563 int (+pad)
#define OFF_REC    25619200ull     // 3.2M int2 = 25,600,000
#define WS_NEEDED  51219200ull

__device__ __forceinline__ unsigned short f2bf(float f) {
    unsigned u = __float_as_uint(f);
    u += 0x7fff + ((u >> 16) & 1);      // round-to-nearest-even
    return (unsigned short)(u >> 16);
}
// word holds (feat w) in low 16, (feat w+64) in high 16
__device__ __forceinline__ float2 bfpair(unsigned u) {
    float2 r;
    r.x = __uint_as_float(u << 16);
    r.y = __uint_as_float(u & 0xffff0000u);
    return r;
}

// ---------------- GEMM: sup16 = bf16(x @ W), paired (f, f+64) layout ----------
__global__ __launch_bounds__(256) void gemm_kernel(const float* __restrict__ x,
                                                   const float* __restrict__ w,
                                                   unsigned* __restrict__ sup16,
                                                   int M) {
    __shared__ float sX[32][64];
    __shared__ float sW[32][128];

    const int tid = threadIdx.x;
    const int r0  = blockIdx.x * 64;
    const int tx  = tid & 31;   // owns cols {2tx, 2tx+1, 2tx+64, 2tx+65}
    const int ty  = tid >> 5;

    float acc[8][4];
#pragma unroll
    for (int r = 0; r < 8; ++r)
#pragma unroll
        for (int c = 0; c < 4; ++c) acc[r][c] = 0.f;

    for (int c0 = 0; c0 < 128; c0 += 32) {
        {
            const int row = tid >> 3;
            const int kk  = (tid & 7) * 4;
#pragma unroll
            for (int h = 0; h < 2; ++h) {
                const int rr = row + h * 32;
                float4 v = make_float4(0.f, 0.f, 0.f, 0.f);
                if (r0 + rr < M)
                    v = *(const float4*)&x[(size_t)(r0 + rr) * D + c0 + kk];
                sX[kk + 0][rr] = v.x;
                sX[kk + 1][rr] = v.y;
                sX[kk + 2][rr] = v.z;
                sX[kk + 3][rr] = v.w;
            }
        }
#pragma unroll
        for (int i = tid; i < 1024; i += 256) {
            const int k  = i >> 5;
            const int c4 = (i & 31) * 4;
            *(float4*)&sW[k][c4] = *(const float4*)&w[(size_t)(c0 + k) * D + c4];
        }
        __syncthreads();

#pragma unroll
        for (int k = 0; k < 32; ++k) {
            const float2 wlo = *(const float2*)&sW[k][tx * 2];
            const float2 whi = *(const float2*)&sW[k][tx * 2 + 64];
            const float4 xa = *(const float4*)&sX[k][ty * 8];
            const float4 xb = *(const float4*)&sX[k][ty * 8 + 4];
            const float xr[8] = {xa.x, xa.y, xa.z, xa.w, xb.x, xb.y, xb.z, xb.w};
#pragma unroll
            for (int r = 0; r < 8; ++r) {
                acc[r][0] += xr[r] * wlo.x;
                acc[r][1] += xr[r] * wlo.y;
                acc[r][2] += xr[r] * whi.x;
                acc[r][3] += xr[r] * whi.y;
            }
        }
        __syncthreads();
    }

#pragma unroll
    for (int r = 0; r < 8; ++r) {
        const int row = r0 + ty * 8 + r;
        if (row < M) {
            uint2 p;
            p.x = (unsigned)f2bf(acc[r][0]) | ((unsigned)f2bf(acc[r][2]) << 16);
            p.y = (unsigned)f2bf(acc[r][1]) | ((unsigned)f2bf(acc[r][3]) << 16);
            *(uint2*)&sup16[(size_t)row * 64 + tx * 2] = p;
        }
    }
}

// ---------------- bucket histogram (LDS-staged) ----------------
__global__ __launch_bounds__(256) void hist_kernel(const int* __restrict__ rows,
                                                   int* __restrict__ bcnt) {
    __shared__ int h[NBUCK];
    for (int i = threadIdx.x; i < NBUCK; i += 256) h[i] = 0;
    __syncthreads();
    const long long base = (long long)blockIdx.x * FILL_CHUNK;
#pragma unroll
    for (int i = 0; i < 12; ++i) {
        const long long e = base + (i * 256 + threadIdx.x) * 4;
        if (e < N_EDGES) {
            const int4 r = *(const int4*)&rows[e];
            atomicAdd(&h[r.x >> 6], 1);
            atomicAdd(&h[r.y >> 6], 1);
            atomicAdd(&h[r.z >> 6], 1);
            atomicAdd(&h[r.w >> 6], 1);
        }
    }
    __syncthreads();
    for (int i = threadIdx.x; i < NBUCK; i += 256)
        if (h[i]) atomicAdd(&bcnt[i], h[i]);
}

// ---------------- exclusive scan over 1563 bucket counts (one block) ----------
__global__ __launch_bounds__(256) void scan_kernel(const int* __restrict__ bcnt,
                                                   int* __restrict__ bstart,
                                                   int* __restrict__ bpos) {
    __shared__ int tsum[256];
    const int t = threadIdx.x;
    int local[7];
    int s = 0;
#pragma unroll
    for (int k = 0; k < 7; ++k) {
        const int idx = t * 7 + k;
        const int v = (idx < NBUCK) ? bcnt[idx] : 0;
        local[k] = v;
        s += v;
    }
    tsum[t] = s;
    __syncthreads();
    for (int off = 1; off < 256; off <<= 1) {
        const int v = (t >= off) ? tsum[t - off] : 0;
        __syncthreads();
        tsum[t] += v;
        __syncthreads();
    }
    int pos = tsum[t] - s;   // exclusive prefix
#pragma unroll
    for (int k = 0; k < 7; ++k) {
        const int idx = t * 7 + k;
        if (idx < NBUCK) {
            bstart[idx] = pos;
            bpos[idx]   = pos;
            pos += local[k];
        }
    }
    if (t == 0) bstart[NBUCK] = N_EDGES;
}

// ---------------- fill: block-batched bucket sort (64 B runs) ----------------
__global__ __launch_bounds__(256) void fill_kernel(const int* __restrict__ rows,
                                                   const int* __restrict__ cols,
                                                   const float* __restrict__ vals,
                                                   int* __restrict__ bpos,
                                                   int2* __restrict__ rec) {
    __shared__ int cnt[NBUCK];
    __shared__ int bas[NBUCK];
    __shared__ unsigned short lrank[FILL_CHUNK];
    const int t = threadIdx.x;
    for (int i = t; i < NBUCK; i += 256) cnt[i] = 0;
    __syncthreads();
    const long long base = (long long)blockIdx.x * FILL_CHUNK;

    // phase 1: per-edge rank within (block, bucket)
#pragma unroll
    for (int i = 0; i < 12; ++i) {
        const int li = (i * 256 + t) * 4;
        const long long e = base + li;
        if (e < N_EDGES) {
            const int4 r = *(const int4*)&rows[e];
            lrank[li + 0] = (unsigned short)atomicAdd(&cnt[r.x >> 6], 1);
            lrank[li + 1] = (unsigned short)atomicAdd(&cnt[r.y >> 6], 1);
            lrank[li + 2] = (unsigned short)atomicAdd(&cnt[r.z >> 6], 1);
            lrank[li + 3] = (unsigned short)atomicAdd(&cnt[r.w >> 6], 1);
        }
    }
    __syncthreads();
    // phase 2: reserve one contiguous run per non-empty bucket
    for (int i = t; i < NBUCK; i += 256)
        bas[i] = cnt[i] ? atomicAdd(&bpos[i], cnt[i]) : 0;
    __syncthreads();
    // phase 3: scatter records into runs
#pragma unroll
    for (int i = 0; i < 12; ++i) {
        const int li = (i * 256 + t) * 4;
        const long long e = base + li;
        if (e < N_EDGES) {
            const int4   r = *(const int4*)&rows[e];
            const int4   c = *(const int4*)&cols[e];
            const float4 v = *(const float4*)&vals[e];
            int p;
            p = bas[r.x >> 6] + lrank[li + 0];
            rec[p] = make_int2(c.x | ((r.x & 63) << 20), __float_as_int(v.x));
            p = bas[r.y >> 6] + lrank[li + 1];
            rec[p] = make_int2(c.y | ((r.y & 63) << 20), __float_as_int(v.y));
            p = bas[r.z >> 6] + lrank[li + 2];
            rec[p] = make_int2(c.z | ((r.z & 63) << 20), __float_as_int(v.z));
            p = bas[r.w >> 6] + lrank[li + 3];
            rec[p] = make_int2(c.w | ((r.w & 63) << 20), __float_as_int(v.w));
        }
    }
}

// ---------------- bucket-gather: LDS fp32 accumulate, fused finalize ---------
__global__ __launch_bounds__(256) void gather_kernel(const unsigned* __restrict__ sup16,
                                                     const int* __restrict__ bstart,
                                                     const int2* __restrict__ rec,
                                                     const float* __restrict__ norm,
                                                     const float* __restrict__ bias,
                                                     float* __restrict__ out) {
    __shared__ float acc[64 * 128];   // [rowlo][feat], 32 KB
    __shared__ int2 ebuf[512];
    const int t = threadIdx.x;
    const int b = blockIdx.x;
#pragma unroll
    for (int i = 0; i < 8; ++i)
        *(float4*)&acc[(i * 256 + t) * 4] = make_float4(0.f, 0.f, 0.f, 0.f);
    const int s0 = bstart[b];
    const int n  = bstart[b + 1] - s0;
    const int wave = t >> 6, lane = t & 63;
    __syncthreads();

    for (int cb = 0; cb < n; cb += 512) {
        const int m = min(512, n - cb);
        for (int k = t; k < m; k += 256) ebuf[k] = rec[s0 + cb + k];
        __syncthreads();
        const int lo = wave * 128;
        const int hi = min(lo + 128, m);
        int j = lo;
        for (; j + 4 <= hi; j += 4) {
            const int2 e0 = ebuf[j], e1 = ebuf[j + 1], e2 = ebuf[j + 2], e3 = ebuf[j + 3];
            const unsigned u0 = sup16[(size_t)(e0.x & 0xFFFFF) * 64 + lane];
            const unsigned u1 = sup16[(size_t)(e1.x & 0xFFFFF) * 64 + lane];
            const unsigned u2 = sup16[(size_t)(e2.x & 0xFFFFF) * 64 + lane];
            const unsigned u3 = sup16[(size_t)(e3.x & 0xFFFFF) * 64 + lane];
            const float v0 = __int_as_float(e0.y);
            const float v1 = __int_as_float(e1.y);
            const float v2 = __int_as_float(e2.y);
            const float v3 = __int_as_float(e3.y);
            float2 p;
            p = bfpair(u0);
            atomicAdd(&acc[((e0.x >> 20) & 63) * 128 + lane],      p.x * v0);
            atomicAdd(&acc[((e0.x >> 20) & 63) * 128 + lane + 64], p.y * v0);
            p = bfpair(u1);
            atomicAdd(&acc[((e1.x >> 20) & 63) * 128 + lane],      p.x * v1);
            atomicAdd(&acc[((e1.x >> 20) & 63) * 128 + lane + 64], p.y * v1);
            p = bfpair(u2);
            atomicAdd(&acc[((e2.x >> 20) & 63) * 128 + lane],      p.x * v2);
            atomicAdd(&acc[((e2.x >> 20) & 63) * 128 + lane + 64], p.y * v2);
            p = bfpair(u3);
            atomicAdd(&acc[((e3.x >> 20) & 63) * 128 + lane],      p.x * v3);
            atomicAdd(&acc[((e3.x >> 20) & 63) * 128 + lane + 64], p.y * v3);
        }
        for (; j < hi; ++j) {
            const int2 e = ebuf[j];
            const unsigned u = sup16[(size_t)(e.x & 0xFFFFF) * 64 + lane];
            const float v = __int_as_float(e.y);
            const float2 p = bfpair(u);
            atomicAdd(&acc[((e.x >> 20) & 63) * 128 + lane],      p.x * v);
            atomicAdd(&acc[((e.x >> 20) & 63) * 128 + lane + 64], p.y * v);
        }
        __syncthreads();
    }

    // epilogue: out = acc / norm + bias
    const int gb = b * 64;
#pragma unroll
    for (int i = 0; i < 8; ++i) {
        const int s = i * 256 + t;
        const int row = s >> 5;
        const int f = (s & 31) * 4;
        const int grow = gb + row;
        if (grow < M_NODES) {
            const float inv = 1.0f / norm[grow];
            const float4 a = *(float4*)&acc[row * 128 + f];
            const float4 bi = *(const float4*)&bias[f];
            float4 o;
            o.x = a.x * inv + bi.x;
            o.y = a.y * inv + bi.y;
            o.z = a.z * inv + bi.z;
            o.w = a.w * inv + bi.w;
            *(float4*)&out[(size_t)grow * D + f] = o;
        }
    }
}

// ---------------- fallback path (fp32 support + atomic scatter) --------------
__global__ __launch_bounds__(256) void gemm32_kernel(const float* __restrict__ x,
                                                     const float* __restrict__ w,
                                                     float* __restrict__ support,
                                                     int M) {
    __shared__ float sX[32][64];
    __shared__ float sW[32][128];
    const int tid = threadIdx.x;
    const int r0  = blockIdx.x * 64;
    const int tx  = tid & 31;
    const int ty  = tid >> 5;
    float acc[8][4];
#pragma unroll
    for (int r = 0; r < 8; ++r)
#pragma unroll
        for (int c = 0; c < 4; ++c) acc[r][c] = 0.f;
    for (int c0 = 0; c0 < 128; c0 += 32) {
        {
            const int row = tid >> 3;
            const int kk  = (tid & 7) * 4;
#pragma unroll
            for (int h = 0; h < 2; ++h) {
                const int rr = row + h * 32;
                float4 v = make_float4(0.f, 0.f, 0.f, 0.f);
                if (r0 + rr < M)
                    v = *(const float4*)&x[(size_t)(r0 + rr) * D + c0 + kk];
                sX[kk + 0][rr] = v.x; sX[kk + 1][rr] = v.y;
                sX[kk + 2][rr] = v.z; sX[kk + 3][rr] = v.w;
            }
        }
#pragma unroll
        for (int i = tid; i < 1024; i += 256) {
            const int k  = i >> 5;
            const int c4 = (i & 31) * 4;
            *(float4*)&sW[k][c4] = *(const float4*)&w[(size_t)(c0 + k) * D + c4];
        }
        __syncthreads();
#pragma unroll
        for (int k = 0; k < 32; ++k) {
            const float4 wv = *(const float4*)&sW[k][tx * 4];
            const float4 xa = *(const float4*)&sX[k][ty * 8];
            const float4 xb = *(const float4*)&sX[k][ty * 8 + 4];
            const float xr[8] = {xa.x, xa.y, xa.z, xa.w, xb.x, xb.y, xb.z, xb.w};
#pragma unroll
            for (int r = 0; r < 8; ++r) {
                acc[r][0] += xr[r] * wv.x; acc[r][1] += xr[r] * wv.y;
                acc[r][2] += xr[r] * wv.z; acc[r][3] += xr[r] * wv.w;
            }
        }
        __syncthreads();
    }
#pragma unroll
    for (int r = 0; r < 8; ++r) {
        const int row = r0 + ty * 8 + r;
        if (row < M)
            *(float4*)&support[(size_t)row * D + tx * 4] =
                make_float4(acc[r][0], acc[r][1], acc[r][2], acc[r][3]);
    }
}

__global__ __launch_bounds__(256) void spmm_kernel(const float* __restrict__ support,
                                                   const int* __restrict__ rows,
                                                   const int* __restrict__ cols,
                                                   const float* __restrict__ vals,
                                                   float* __restrict__ out) {
    const long long t = (long long)blockIdx.x * 256 + threadIdx.x;
    const int e = (int)(t >> 5);
    if (e >= N_EDGES) return;
    const int f   = (int)(t & 31) * 4;
    const int src = cols[e];
    const int dst = rows[e];
    const float v = vals[e];
    const float4 s = *(const float4*)&support[(size_t)src * D + f];
    float* o = &out[(size_t)dst * D + f];
    atomicAdd(o + 0, s.x * v);
    atomicAdd(o + 1, s.y * v);
    atomicAdd(o + 2, s.z * v);
    atomicAdd(o + 3, s.w * v);
}

__global__ __launch_bounds__(256) void finalize_kernel(float* __restrict__ out,
                                                       const float* __restrict__ norm,
                                                       const float* __restrict__ bias) {
    const int t = blockIdx.x * 256 + threadIdx.x;
    const int nrow = t >> 5;
    if (nrow >= M_NODES) return;
    const int f = (t & 31) * 4;
    const float inv = 1.0f / norm[nrow];
    float4 o = *(float4*)&out[(size_t)nrow * D + f];
    const float4 b = *(const float4*)&bias[f];
    o.x = o.x * inv + b.x; o.y = o.y * inv + b.y;
    o.z = o.z * inv + b.z; o.w = o.w * inv + b.w;
    *(float4*)&out[(size_t)nrow * D + f] = o;
}

extern "C" void kernel_launch(void* const* d_in, const int* in_sizes, int n_in,
                              void* d_out, int out_size, void* d_ws, size_t ws_size,
                              hipStream_t stream) {
    const float* x    = (const float*)d_in[0];
    const float* w    = (const float*)d_in[1];
    const float* bias = (const float*)d_in[2];
    const int*   rows = (const int*)d_in[3];
    const int*   cols = (const int*)d_in[4];
    const float* vals = (const float*)d_in[5];
    const float* norm = (const float*)d_in[6];
    float* out = (float*)d_out;
    char* ws = (char*)d_ws;

    if (ws_size >= WS_NEEDED) {
        unsigned* sup16  = (unsigned*)(ws + OFF_SUP16);
        int*      bcnt   = (int*)(ws + OFF_BCNT);
        int*      bstart = (int*)(ws + OFF_BSTART);
        int*      bpos   = (int*)(ws + OFF_BPOS);
        int2*     rec    = (int2*)(ws + OFF_REC);

        gemm_kernel<<<(M_NODES + 63) / 64, 256, 0, stream>>>(x, w, sup16, M_NODES);

        hipMemsetAsync(bcnt, 0, NBUCK * sizeof(int), stream);
        hist_kernel<<<FILL_BLOCKS, 256, 0, stream>>>(rows, bcnt);
        scan_kernel<<<1, 256, 0, stream>>>(bcnt, bstart, bpos);
        fill_kernel<<<FILL_BLOCKS, 256, 0, stream>>>(rows, cols, vals, bpos, rec);

        gather_kernel<<<NBUCK, 256, 0, stream>>>(sup16, bstart, rec, norm, bias, out);
    } else {
        // fallback: fp32 support + atomic scatter
        float* support = (float*)ws;
        gemm32_kernel<<<(M_NODES + 63) / 64, 256, 0, stream>>>(x, w, support, M_NODES);
        hipMemsetAsync(d_out, 0, (size_t)out_size * sizeof(float), stream);
        const long long spmm_threads = (long long)N_EDGES * 32;
        spmm_kernel<<<(int)((spmm_threads + 255) / 256), 256, 0, stream>>>(support, rows, cols, vals, out);
        finalize_kernel<<<(M_NODES * 32 + 255) / 256, 256, 0, stream>>>(out, norm, bias);
    }
}

// Round 6
// 403.934 us; speedup vs baseline: 6.5015x; 6.5015x over previous
//
#include <hip/hip_runtime.h>

#define M_NODES 100000
#define N_EDGES 3200000
#define D 128
#define NBUCK 1563            // ceil(100000 / 64) buckets of 64 rows
#define FILL_CHUNK 12288      // edges per block in hist/fill (256 thr * 12 * 4)
#define FILL_BLOCKS 261       // ceil(3.2M / 12288)

// ---------------- workspace layout (bytes) ----------------
#define OFF_SUP16  0ull            // 100000*64 u32 (paired bf16) = 25,600,000
#define OFF_BCNT   25600000ull     // 1563 int (+pad)
#define OFF_BSTART 25606400ull     // 1564 int (+pad)
#define OFF_BPOS   25612800ull     // 1563 int (+pad)
#define OFF_RSTART 25619200ull     // 100001 int (+pad)
#define OFF_REC    26019328ull     // 3.2M int2 = 25,600,000 (bucket-sorted)
#define OFF_REC2   51619328ull     // 3.2M int2 = 25,600,000 (row-sorted)
#define WS_NEEDED  77219328ull

__device__ __forceinline__ unsigned short f2bf(float f) {
    unsigned u = __float_as_uint(f);
    u += 0x7fff + ((u >> 16) & 1);      // round-to-nearest-even
    return (unsigned short)(u >> 16);
}
// word k of a row holds features (2k, 2k+1)
__device__ __forceinline__ float2 bfpair(unsigned u) {
    float2 r;
    r.x = __uint_as_float(u << 16);
    r.y = __uint_as_float(u & 0xffff0000u);
    return r;
}

// ---------------- GEMM: sup16 = bf16(x @ W), word k = (2k, 2k+1) -------------
__global__ __launch_bounds__(256) void gemm_kernel(const float* __restrict__ x,
                                                   const float* __restrict__ w,
                                                   unsigned* __restrict__ sup16,
                                                   int M) {
    __shared__ float sX[32][64];
    __shared__ float sW[32][128];

    const int tid = threadIdx.x;
    const int r0  = blockIdx.x * 64;
    const int tx  = tid & 31;
    const int ty  = tid >> 5;

    float acc[8][4];
#pragma unroll
    for (int r = 0; r < 8; ++r)
#pragma unroll
        for (int c = 0; c < 4; ++c) acc[r][c] = 0.f;

    for (int c0 = 0; c0 < 128; c0 += 32) {
        {
            const int row = tid >> 3;
            const int kk  = (tid & 7) * 4;
#pragma unroll
            for (int h = 0; h < 2; ++h) {
                const int rr = row + h * 32;
                float4 v = make_float4(0.f, 0.f, 0.f, 0.f);
                if (r0 + rr < M)
                    v = *(const float4*)&x[(size_t)(r0 + rr) * D + c0 + kk];
                sX[kk + 0][rr] = v.x;
                sX[kk + 1][rr] = v.y;
                sX[kk + 2][rr] = v.z;
                sX[kk + 3][rr] = v.w;
            }
        }
#pragma unroll
        for (int i = tid; i < 1024; i += 256) {
            const int k  = i >> 5;
            const int c4 = (i & 31) * 4;
            *(float4*)&sW[k][c4] = *(const float4*)&w[(size_t)(c0 + k) * D + c4];
        }
        __syncthreads();

#pragma unroll
        for (int k = 0; k < 32; ++k) {
            const float4 wv = *(const float4*)&sW[k][tx * 4];
            const float4 xa = *(const float4*)&sX[k][ty * 8];
            const float4 xb = *(const float4*)&sX[k][ty * 8 + 4];
            const float xr[8] = {xa.x, xa.y, xa.z, xa.w, xb.x, xb.y, xb.z, xb.w};
#pragma unroll
            for (int r = 0; r < 8; ++r) {
                acc[r][0] += xr[r] * wv.x;
                acc[r][1] += xr[r] * wv.y;
                acc[r][2] += xr[r] * wv.z;
                acc[r][3] += xr[r] * wv.w;
            }
        }
        __syncthreads();
    }

#pragma unroll
    for (int r = 0; r < 8; ++r) {
        const int row = r0 + ty * 8 + r;
        if (row < M) {
            uint2 p;
            p.x = (unsigned)f2bf(acc[r][0]) | ((unsigned)f2bf(acc[r][1]) << 16);
            p.y = (unsigned)f2bf(acc[r][2]) | ((unsigned)f2bf(acc[r][3]) << 16);
            *(uint2*)&sup16[(size_t)row * 64 + tx * 2] = p;
        }
    }
}

// ---------------- bucket histogram (LDS-staged) ----------------
__global__ __launch_bounds__(256) void hist_kernel(const int* __restrict__ rows,
                                                   int* __restrict__ bcnt) {
    __shared__ int h[NBUCK];
    for (int i = threadIdx.x; i < NBUCK; i += 256) h[i] = 0;
    __syncthreads();
    const long long base = (long long)blockIdx.x * FILL_CHUNK;
#pragma unroll
    for (int i = 0; i < 12; ++i) {
        const long long e = base + (i * 256 + threadIdx.x) * 4;
        if (e < N_EDGES) {
            const int4 r = *(const int4*)&rows[e];
            atomicAdd(&h[r.x >> 6], 1);
            atomicAdd(&h[r.y >> 6], 1);
            atomicAdd(&h[r.z >> 6], 1);
            atomicAdd(&h[r.w >> 6], 1);
        }
    }
    __syncthreads();
    for (int i = threadIdx.x; i < NBUCK; i += 256)
        if (h[i]) atomicAdd(&bcnt[i], h[i]);
}

// ---------------- exclusive scan over 1563 bucket counts (one block) ----------
__global__ __launch_bounds__(256) void scan_kernel(const int* __restrict__ bcnt,
                                                   int* __restrict__ bstart,
                                                   int* __restrict__ bpos,
                                                   int* __restrict__ row_start) {
    __shared__ int tsum[256];
    const int t = threadIdx.x;
    int local[7];
    int s = 0;
#pragma unroll
    for (int k = 0; k < 7; ++k) {
        const int idx = t * 7 + k;
        const int v = (idx < NBUCK) ? bcnt[idx] : 0;
        local[k] = v;
        s += v;
    }
    tsum[t] = s;
    __syncthreads();
    for (int off = 1; off < 256; off <<= 1) {
        const int v = (t >= off) ? tsum[t - off] : 0;
        __syncthreads();
        tsum[t] += v;
        __syncthreads();
    }
    int pos = tsum[t] - s;   // exclusive prefix
#pragma unroll
    for (int k = 0; k < 7; ++k) {
        const int idx = t * 7 + k;
        if (idx < NBUCK) {
            bstart[idx] = pos;
            bpos[idx]   = pos;
            pos += local[k];
        }
    }
    if (t == 0) {
        bstart[NBUCK] = N_EDGES;
        row_start[M_NODES] = N_EDGES;
    }
}

// ---------------- fill: block-batched bucket sort (rowlo packed in .x) -------
__global__ __launch_bounds__(256) void fill_kernel(const int* __restrict__ rows,
                                                   const int* __restrict__ cols,
                                                   const float* __restrict__ vals,
                                                   int* __restrict__ bpos,
                                                   int2* __restrict__ rec) {
    __shared__ int cnt[NBUCK];
    __shared__ int bas[NBUCK];
    __shared__ unsigned short lrank[FILL_CHUNK];
    const int t = threadIdx.x;
    for (int i = t; i < NBUCK; i += 256) cnt[i] = 0;
    __syncthreads();
    const long long base = (long long)blockIdx.x * FILL_CHUNK;

    // phase 1: per-edge rank within (block, bucket)
#pragma unroll
    for (int i = 0; i < 12; ++i) {
        const int li = (i * 256 + t) * 4;
        const long long e = base + li;
        if (e < N_EDGES) {
            const int4 r = *(const int4*)&rows[e];
            lrank[li + 0] = (unsigned short)atomicAdd(&cnt[r.x >> 6], 1);
            lrank[li + 1] = (unsigned short)atomicAdd(&cnt[r.y >> 6], 1);
            lrank[li + 2] = (unsigned short)atomicAdd(&cnt[r.z >> 6], 1);
            lrank[li + 3] = (unsigned short)atomicAdd(&cnt[r.w >> 6], 1);
        }
    }
    __syncthreads();
    // phase 2: reserve one contiguous run per non-empty bucket
    for (int i = t; i < NBUCK; i += 256)
        bas[i] = cnt[i] ? atomicAdd(&bpos[i], cnt[i]) : 0;
    __syncthreads();
    // phase 3: scatter records into runs
#pragma unroll
    for (int i = 0; i < 12; ++i) {
        const int li = (i * 256 + t) * 4;
        const long long e = base + li;
        if (e < N_EDGES) {
            const int4   r = *(const int4*)&rows[e];
            const int4   c = *(const int4*)&cols[e];
            const float4 v = *(const float4*)&vals[e];
            int p;
            p = bas[r.x >> 6] + lrank[li + 0];
            rec[p] = make_int2(c.x | ((r.x & 63) << 20), __float_as_int(v.x));
            p = bas[r.y >> 6] + lrank[li + 1];
            rec[p] = make_int2(c.y | ((r.y & 63) << 20), __float_as_int(v.y));
            p = bas[r.z >> 6] + lrank[li + 2];
            rec[p] = make_int2(c.z | ((r.z & 63) << 20), __float_as_int(v.z));
            p = bas[r.w >> 6] + lrank[li + 3];
            rec[p] = make_int2(c.w | ((r.w & 63) << 20), __float_as_int(v.w));
        }
    }
}

// ---------------- refine: bucket -> exact row order (one block per bucket) ---
// Bucket size is ~2048 (binomial, 64/100000 of 3.2M); 4096 capacity is >40 sigma.
__global__ __launch_bounds__(256) void refine_kernel(const int2* __restrict__ rec,
                                                     const int* __restrict__ bstart,
                                                     int2* __restrict__ rec2,
                                                     int* __restrict__ row_start) {
    __shared__ int cnt[64];
    __shared__ int base64[64];
    __shared__ unsigned short lrank[4096];
    const int t = threadIdx.x;
    const int b = blockIdx.x;
    if (t < 64) cnt[t] = 0;
    __syncthreads();
    const int s0 = bstart[b];
    const int n  = min(bstart[b + 1] - s0, 4096);   // defensive clamp (cap >40 sigma)

    // phase 1: rank within (bucket, row)
    for (int k = t; k < n; k += 256) {
        const int rl = (rec[s0 + k].x >> 20) & 63;
        lrank[k] = (unsigned short)atomicAdd(&cnt[rl], 1);
    }
    __syncthreads();
    // phase 2: serial exclusive scan of 64 counts
    if (t == 0) {
        int run = s0;
#pragma unroll
        for (int i = 0; i < 64; ++i) {
            base64[i] = run;
            run += cnt[i];
        }
    }
    __syncthreads();
    const int grow = b * 64 + t;
    if (t < 64 && grow < M_NODES) row_start[grow] = base64[t];
    // phase 3: scatter to exact row position (contiguous 16 KB range -> L2 WC)
    for (int k = t; k < n; k += 256) {
        const int2 e = rec[s0 + k];
        rec2[base64[(e.x >> 20) & 63] + lrank[k]] = make_int2(e.x & 0xFFFFF, e.y);
    }
}

// ---------------- gather-reduce: one wave per row, fused finalize ------------
__global__ __launch_bounds__(256) void gather_kernel(const unsigned* __restrict__ sup16,
                                                     const int* __restrict__ row_start,
                                                     const int2* __restrict__ edges,
                                                     const float* __restrict__ norm,
                                                     const float* __restrict__ bias,
                                                     float* __restrict__ out) {
    const int row  = (blockIdx.x * 256 + threadIdx.x) >> 6;   // one wave per row
    const int lane = threadIdx.x & 63;
    if (row >= M_NODES) return;

    const int s0 = row_start[row];
    const int s1 = row_start[row + 1];

    float2 acc = make_float2(0.f, 0.f);
    int j = s0;
    for (; j + 8 <= s1; j += 8) {
        int2 e[8];
#pragma unroll
        for (int q = 0; q < 8; ++q) e[q] = edges[j + q];
        unsigned u[8];
#pragma unroll
        for (int q = 0; q < 8; ++q) u[q] = sup16[(size_t)e[q].x * 64 + lane];
#pragma unroll
        for (int q = 0; q < 8; ++q) {
            const float v = __int_as_float(e[q].y);
            const float2 p = bfpair(u[q]);
            acc.x += p.x * v;
            acc.y += p.y * v;
        }
    }
    for (; j < s1; ++j) {
        const int2 e = edges[j];
        const unsigned u = sup16[(size_t)e.x * 64 + lane];
        const float v = __int_as_float(e.y);
        const float2 p = bfpair(u);
        acc.x += p.x * v;
        acc.y += p.y * v;
    }

    const int fo = lane * 2;
    const float inv = 1.0f / norm[row];
    const float2 b2 = *(const float2*)&bias[fo];
    float2 o;
    o.x = acc.x * inv + b2.x;
    o.y = acc.y * inv + b2.y;
    *(float2*)&out[(size_t)row * D + fo] = o;
}

// ---------------- fallback path (fp32 support + atomic scatter) --------------
__global__ __launch_bounds__(256) void gemm32_kernel(const float* __restrict__ x,
                                                     const float* __restrict__ w,
                                                     float* __restrict__ support,
                                                     int M) {
    __shared__ float sX[32][64];
    __shared__ float sW[32][128];
    const int tid = threadIdx.x;
    const int r0  = blockIdx.x * 64;
    const int tx  = tid & 31;
    const int ty  = tid >> 5;
    float acc[8][4];
#pragma unroll
    for (int r = 0; r < 8; ++r)
#pragma unroll
        for (int c = 0; c < 4; ++c) acc[r][c] = 0.f;
    for (int c0 = 0; c0 < 128; c0 += 32) {
        {
            const int row = tid >> 3;
            const int kk  = (tid & 7) * 4;
#pragma unroll
            for (int h = 0; h < 2; ++h) {
                const int rr = row + h * 32;
                float4 v = make_float4(0.f, 0.f, 0.f, 0.f);
                if (r0 + rr < M)
                    v = *(const float4*)&x[(size_t)(r0 + rr) * D + c0 + kk];
                sX[kk + 0][rr] = v.x; sX[kk + 1][rr] = v.y;
                sX[kk + 2][rr] = v.z; sX[kk + 3][rr] = v.w;
            }
        }
#pragma unroll
        for (int i = tid; i < 1024; i += 256) {
            const int k  = i >> 5;
            const int c4 = (i & 31) * 4;
            *(float4*)&sW[k][c4] = *(const float4*)&w[(size_t)(c0 + k) * D + c4];
        }
        __syncthreads();
#pragma unroll
        for (int k = 0; k < 32; ++k) {
            const float4 wv = *(const float4*)&sW[k][tx * 4];
            const float4 xa = *(const float4*)&sX[k][ty * 8];
            const float4 xb = *(const float4*)&sX[k][ty * 8 + 4];
            const float xr[8] = {xa.x, xa.y, xa.z, xa.w, xb.x, xb.y, xb.z, xb.w};
#pragma unroll
            for (int r = 0; r < 8; ++r) {
                acc[r][0] += xr[r] * wv.x; acc[r][1] += xr[r] * wv.y;
                acc[r][2] += xr[r] * wv.z; acc[r][3] += xr[r] * wv.w;
            }
        }
        __syncthreads();
    }
#pragma unroll
    for (int r = 0; r < 8; ++r) {
        const int row = r0 + ty * 8 + r;
        if (row < M)
            *(float4*)&support[(size_t)row * D + tx * 4] =
                make_float4(acc[r][0], acc[r][1], acc[r][2], acc[r][3]);
    }
}

__global__ __launch_bounds__(256) void spmm_kernel(const float* __restrict__ support,
                                                   const int* __restrict__ rows,
                                                   const int* __restrict__ cols,
                                                   const float* __restrict__ vals,
                                                   float* __restrict__ out) {
    const long long t = (long long)blockIdx.x * 256 + threadIdx.x;
    const int e = (int)(t >> 5);
    if (e >= N_EDGES) return;
    const int f   = (int)(t & 31) * 4;
    const int src = cols[e];
    const int dst = rows[e];
    const float v = vals[e];
    const float4 s = *(const float4*)&support[(size_t)src * D + f];
    float* o = &out[(size_t)dst * D + f];
    atomicAdd(o + 0, s.x * v);
    atomicAdd(o + 1, s.y * v);
    atomicAdd(o + 2, s.z * v);
    atomicAdd(o + 3, s.w * v);
}

__global__ __launch_bounds__(256) void finalize_kernel(float* __restrict__ out,
                                                       const float* __restrict__ norm,
                                                       const float* __restrict__ bias) {
    const int t = blockIdx.x * 256 + threadIdx.x;
    const int nrow = t >> 5;
    if (nrow >= M_NODES) return;
    const int f = (t & 31) * 4;
    const float inv = 1.0f / norm[nrow];
    float4 o = *(float4*)&out[(size_t)nrow * D + f];
    const float4 b = *(const float4*)&bias[f];
    o.x = o.x * inv + b.x; o.y = o.y * inv + b.y;
    o.z = o.z * inv + b.z; o.w = o.w * inv + b.w;
    *(float4*)&out[(size_t)nrow * D + f] = o;
}

extern "C" void kernel_launch(void* const* d_in, const int* in_sizes, int n_in,
                              void* d_out, int out_size, void* d_ws, size_t ws_size,
                              hipStream_t stream) {
    const float* x    = (const float*)d_in[0];
    const float* w    = (const float*)d_in[1];
    const float* bias = (const float*)d_in[2];
    const int*   rows = (const int*)d_in[3];
    const int*   cols = (const int*)d_in[4];
    const float* vals = (const float*)d_in[5];
    const float* norm = (const float*)d_in[6];
    float* out = (float*)d_out;
    char* ws = (char*)d_ws;

    if (ws_size >= WS_NEEDED) {
        unsigned* sup16     = (unsigned*)(ws + OFF_SUP16);
        int*      bcnt      = (int*)(ws + OFF_BCNT);
        int*      bstart    = (int*)(ws + OFF_BSTART);
        int*      bpos      = (int*)(ws + OFF_BPOS);
        int*      row_start = (int*)(ws + OFF_RSTART);
        int2*     rec       = (int2*)(ws + OFF_REC);
        int2*     rec2      = (int2*)(ws + OFF_REC2);

        gemm_kernel<<<(M_NODES + 63) / 64, 256, 0, stream>>>(x, w, sup16, M_NODES);

        hipMemsetAsync(bcnt, 0, NBUCK * sizeof(int), stream);
        hist_kernel<<<FILL_BLOCKS, 256, 0, stream>>>(rows, bcnt);
        scan_kernel<<<1, 256, 0, stream>>>(bcnt, bstart, bpos, row_start);
        fill_kernel<<<FILL_BLOCKS, 256, 0, stream>>>(rows, cols, vals, bpos, rec);
        refine_kernel<<<NBUCK, 256, 0, stream>>>(rec, bstart, rec2, row_start);

        const int gblocks = (M_NODES * 64 + 255) / 256;   // one wave per row
        gather_kernel<<<gblocks, 256, 0, stream>>>(sup16, row_start, rec2,
                                                   norm, bias, out);
    } else {
        // fallback: fp32 support + atomic scatter
        float* support = (float*)ws;
        gemm32_kernel<<<(M_NODES + 63) / 64, 256, 0, stream>>>(x, w, support, M_NODES);
        hipMemsetAsync(d_out, 0, (size_t)out_size * sizeof(float), stream);
        const long long spmm_threads = (long long)N_EDGES * 32;
        spmm_kernel<<<(int)((spmm_threads + 255) / 256), 256, 0, stream>>>(support, rows, cols, vals, out);
        finalize_kernel<<<(M_NODES * 32 + 255) / 256, 256, 0, stream>>>(out, norm, bias);
    }
}